// Round 2
// baseline (1025.621 us; speedup 1.0000x reference)
//
#include <hip/hip_runtime.h>
#include <hip/hip_bf16.h>

typedef unsigned short u16;
typedef __bf16 bf16x8 __attribute__((ext_vector_type(8)));
typedef float f32x4 __attribute__((ext_vector_type(4)));

#define NN 100000
#define NE 800000
#define NGRAPH 1024
#define KREP 10
#define HD 512
#define MQ 10240
#define FCN 256
#define EPS 1e-5f

static __device__ __forceinline__ float bf2f(u16 u) {
  unsigned int x = ((unsigned int)u) << 16;
  float f; __builtin_memcpy(&f, &x, 4); return f;
}
static __device__ __forceinline__ u16 f2bf(float f) {
  __hip_bfloat16 h = __float2bfloat16(f);
  u16 u; __builtin_memcpy(&u, &h, 2); return u;
}

// ---------------- K1: h0 = node_h @ w_init + b_init  ([N,20]f32 x [20,512]f32 -> bf16) ----------------
__global__ __launch_bounds__(256) void k_init(const float* __restrict__ nh, const float* __restrict__ w,
                                              const float* __restrict__ bi, u16* __restrict__ h) {
  __shared__ float wls[20 * 512];
  __shared__ float als[16 * 20];
  int t = threadIdx.x;
  for (int i = t; i < 20 * 512; i += 256) wls[i] = w[i];
  int v0 = blockIdx.x * 16;
  for (int i = t; i < 16 * 20; i += 256) {
    int node = v0 + i / 20;
    als[i] = (node < NN) ? nh[node * 20 + i % 20] : 0.0f;
  }
  __syncthreads();
  int c0 = t * 2;
  float b0 = bi[c0], b1 = bi[c0 + 1];
  for (int ni = 0; ni < 16; ni++) {
    int v = v0 + ni; if (v >= NN) break;
    float s0 = b0, s1 = b1;
#pragma unroll
    for (int k = 0; k < 20; k++) {
      float a = als[ni * 20 + k];
      s0 += a * wls[k * 512 + c0];
      s1 += a * wls[k * 512 + c0 + 1];
    }
    ushort2 o; o.x = f2bf(s0); o.y = f2bf(s1);
    *(ushort2*)&h[(size_t)v * HD + c0] = o;
  }
}

// ---------------- CSR build ----------------
__global__ void k_deg(const int* __restrict__ dst, int* __restrict__ deg) {
  int i = blockIdx.x * 256 + threadIdx.x;
  if (i < NE) atomicAdd(&deg[dst[i]], 1);
}

__global__ __launch_bounds__(256) void k_scan_part(const int* __restrict__ deg, int* __restrict__ part) {
  __shared__ int ls[256];
  int t = threadIdx.x; int base = blockIdx.x * 1024;
  int s = 0;
  for (int i = t; i < 1024; i += 256) { int idx = base + i; if (idx < NN) s += deg[idx]; }
  ls[t] = s; __syncthreads();
  for (int o = 128; o > 0; o >>= 1) { if (t < o) ls[t] += ls[t + o]; __syncthreads(); }
  if (t == 0) part[blockIdx.x] = ls[0];
}

__global__ void k_scan_mid(int* part, int nb, int* offs) {
  __shared__ int ls[128];
  int t = threadIdx.x;
  if (t < nb) ls[t] = part[t];
  __syncthreads();
  if (t == 0) {
    int run = 0;
    for (int i = 0; i < nb; i++) { int v = ls[i]; ls[i] = run; run += v; }
  }
  __syncthreads();
  if (t < nb) part[t] = ls[t];
  if (t == 0) offs[NN] = NE;
}

__global__ __launch_bounds__(256) void k_scan_apply(const int* __restrict__ deg, const int* __restrict__ part,
                                                    int* __restrict__ offs) {
  __shared__ int ls[256];
  int t = threadIdx.x; int base = blockIdx.x * 1024 + t * 4;
  int v[4]; int s = 0;
#pragma unroll
  for (int j = 0; j < 4; j++) { int idx = base + j; v[j] = (idx < NN) ? deg[idx] : 0; s += v[j]; }
  ls[t] = s; __syncthreads();
  for (int o = 1; o < 256; o <<= 1) {
    int x = (t >= o) ? ls[t - o] : 0;
    __syncthreads();
    ls[t] += x;
    __syncthreads();
  }
  int excl = ls[t] - s + part[blockIdx.x];
#pragma unroll
  for (int j = 0; j < 4; j++) { int idx = base + j; if (idx < NN) offs[idx] = excl; excl += v[j]; }
}

__global__ void k_copy(const int* __restrict__ a, int* __restrict__ b) {
  int i = blockIdx.x * 256 + threadIdx.x; if (i < NN) b[i] = a[i];
}

__global__ void k_fill(const int* __restrict__ src, const int* __restrict__ dst,
                       int* __restrict__ cursor, int* __restrict__ nsrc) {
  int i = blockIdx.x * 256 + threadIdx.x;
  if (i < NE) { int p = atomicAdd(&cursor[dst[i]], 1); nsrc[p] = src[i]; }
}

// ---------------- K5: GIN mean gather + column stats (bf16 in/out, f32 stats) ----------------
__global__ __launch_bounds__(256) void k_gin(const u16* __restrict__ hin, const int* __restrict__ offs,
                                             const int* __restrict__ nsrc, u16* __restrict__ x,
                                             float* __restrict__ cs, float* __restrict__ cq) {
  int t = threadIdx.x; int c0 = t * 2;
  float s0 = 0, s1 = 0, q0 = 0, q1 = 0;
  int v0 = blockIdx.x * 64;
  for (int vi = 0; vi < 64; vi++) {
    int v = v0 + vi; if (v >= NN) break;
    int e0 = offs[v], e1 = offs[v + 1];
    float a0 = 0, a1 = 0;
    for (int e = e0; e < e1; e++) {
      int sn = nsrc[e];
      ushort2 u = *(const ushort2*)&hin[(size_t)sn * HD + c0];
      a0 += bf2f(u.x); a1 += bf2f(u.y);
    }
    float inv = 1.0f / fmaxf((float)(e1 - e0), 1.0f);
    ushort2 hu = *(const ushort2*)&hin[(size_t)v * HD + c0];
    float x0 = bf2f(hu.x) + a0 * inv, x1 = bf2f(hu.y) + a1 * inv;
    ushort2 o; o.x = f2bf(x0); o.y = f2bf(x1);
    *(ushort2*)&x[(size_t)v * HD + c0] = o;
    // accumulate stats on the bf16-rounded stored value for self-consistency
    x0 = bf2f(o.x); x1 = bf2f(o.y);
    s0 += x0; s1 += x1; q0 += x0 * x0; q1 += x1 * x1;
  }
  atomicAdd(&cs[c0], s0); atomicAdd(&cs[c0 + 1], s1);
  atomicAdd(&cq[c0], q0); atomicAdd(&cq[c0 + 1], q1);
}

// ---------------- K6: BN(train) + ReLU over [N,512] bf16, f32 params ----------------
__global__ __launch_bounds__(256) void k_bn_hd(const u16* __restrict__ x, const float* __restrict__ cs,
                                               const float* __restrict__ cq, const float* __restrict__ g,
                                               const float* __restrict__ be, u16* __restrict__ y) {
  const float invn = 1.0f / (float)NN;
  size_t total = (size_t)NN * 256;  // ushort2 pairs
  for (size_t i = (size_t)blockIdx.x * 256 + threadIdx.x; i < total; i += (size_t)gridDim.x * 256) {
    int c0 = ((int)(i & 255)) * 2;
    float m0 = cs[c0] * invn, m1 = cs[c0 + 1] * invn;
    float var0 = cq[c0] * invn - m0 * m0, var1 = cq[c0 + 1] * invn - m1 * m1;
    float sc0 = g[c0] * rsqrtf(var0 + EPS), sc1 = g[c0 + 1] * rsqrtf(var1 + EPS);
    float sh0 = be[c0] - m0 * sc0, sh1 = be[c0 + 1] - m1 * sc1;
    ushort2 u = *(const ushort2*)&x[i * 2];
    float y0 = fmaxf(bf2f(u.x) * sc0 + sh0, 0.0f), y1 = fmaxf(bf2f(u.y) * sc1 + sh1, 0.0f);
    ushort2 o; o.x = f2bf(y0); o.y = f2bf(y1);
    *(ushort2*)&y[i * 2] = o;
  }
}

// ---------------- K7: per-graph mean pooling (node_graph sorted) ----------------
__global__ __launch_bounds__(256) void k_pool(const u16* __restrict__ h, const int* __restrict__ ngr,
                                              u16* __restrict__ qemb) {
  int g = blockIdx.x; int t = threadIdx.x;
  int lo = 0, hi = NN;
  while (lo < hi) { int mid = (lo + hi) >> 1; if (ngr[mid] < g) lo = mid + 1; else hi = mid; }
  int s = lo;
  hi = NN;
  while (lo < hi) { int mid = (lo + hi) >> 1; if (ngr[mid] < g + 1) lo = mid + 1; else hi = mid; }
  int e = lo;
  int c0 = t * 2; float a0 = 0, a1 = 0;
  for (int v = s; v < e; v++) {
    ushort2 u = *(const ushort2*)&h[(size_t)v * HD + c0];
    a0 += bf2f(u.x); a1 += bf2f(u.y);
  }
  float inv = 1.0f / fmaxf((float)(e - s), 1.0f);
  ushort2 o; o.x = f2bf(a0 * inv); o.y = f2bf(a1 * inv);
  *(ushort2*)&qemb[(size_t)g * HD + c0] = o;
}

// ---------------- K8: build A = [qemb | pg_emb | neigh_emb]  ([10240,1536] bf16) ----------------
__global__ void k_buildA(const u16* __restrict__ qemb, const float* __restrict__ pg,
                         const float* __restrict__ ne, u16* __restrict__ A) {
  int idx = blockIdx.x * 256 + threadIdx.x;  // chunks of 4 elems
  if (idx >= MQ * 384) return;
  int r = idx / 384; int cc = (idx % 384) * 4;
  int g = r / KREP;
  ushort4 o;
  if (cc < 512) {
    o = *(const ushort4*)&qemb[g * HD + cc];
  } else if (cc < 1024) {
    float4 v = *(const float4*)&pg[(size_t)g * HD + cc - 512];
    o.x = f2bf(v.x); o.y = f2bf(v.y); o.z = f2bf(v.z); o.w = f2bf(v.w);
  } else {
    float4 v = *(const float4*)&ne[(size_t)r * HD + cc - 1024];
    o.x = f2bf(v.x); o.y = f2bf(v.y); o.z = f2bf(v.z); o.w = f2bf(v.w);
  }
  *(ushort4*)&A[(size_t)idx * 4] = o;
}

// ---------------- K9: GEMM C[M,256] = A[M,Kd](bf16) @ W[Kd,256](f32) + bias(f32) -> bf16 ----------------
__global__ __launch_bounds__(256) void k_gemm(const u16* __restrict__ A, const float* __restrict__ W,
                                              const float* __restrict__ bias, u16* __restrict__ C, int Kd) {
  __shared__ __align__(16) u16 Als[64][40];
  __shared__ __align__(16) u16 Bls[64][40];
  int t = threadIdx.x; int wid = t >> 6; int lane = t & 63;
  int m0 = blockIdx.x * 64, n0 = blockIdx.y * 64;
  int wr = wid >> 1, wc = wid & 1;
  f32x4 zero = {0.0f, 0.0f, 0.0f, 0.0f};
  f32x4 acc[2][2];
#pragma unroll
  for (int i = 0; i < 2; i++)
#pragma unroll
    for (int j = 0; j < 2; j++) acc[i][j] = zero;
  int ar = t >> 2, akc = (t & 3) * 8;
  int bk = t >> 3, bnc = (t & 7) * 8;
  int row = lane & 15, kc = (lane >> 4) * 8;
  for (int k0 = 0; k0 < Kd; k0 += 32) {
    *(int4*)&Als[ar][akc] = *(const int4*)&A[(size_t)(m0 + ar) * Kd + k0 + akc];
    float4 w0 = *(const float4*)&W[(size_t)(k0 + bk) * FCN + n0 + bnc];
    float4 w1 = *(const float4*)&W[(size_t)(k0 + bk) * FCN + n0 + bnc + 4];
    Bls[bnc + 0][bk] = f2bf(w0.x); Bls[bnc + 1][bk] = f2bf(w0.y);
    Bls[bnc + 2][bk] = f2bf(w0.z); Bls[bnc + 3][bk] = f2bf(w0.w);
    Bls[bnc + 4][bk] = f2bf(w1.x); Bls[bnc + 5][bk] = f2bf(w1.y);
    Bls[bnc + 6][bk] = f2bf(w1.z); Bls[bnc + 7][bk] = f2bf(w1.w);
    __syncthreads();
    bf16x8 a0 = *(const bf16x8*)&Als[wr * 32 + row][kc];
    bf16x8 a1 = *(const bf16x8*)&Als[wr * 32 + 16 + row][kc];
    bf16x8 b0 = *(const bf16x8*)&Bls[wc * 32 + row][kc];
    bf16x8 b1 = *(const bf16x8*)&Bls[wc * 32 + 16 + row][kc];
    acc[0][0] = __builtin_amdgcn_mfma_f32_16x16x32_bf16(a0, b0, acc[0][0], 0, 0, 0);
    acc[0][1] = __builtin_amdgcn_mfma_f32_16x16x32_bf16(a0, b1, acc[0][1], 0, 0, 0);
    acc[1][0] = __builtin_amdgcn_mfma_f32_16x16x32_bf16(a1, b0, acc[1][0], 0, 0, 0);
    acc[1][1] = __builtin_amdgcn_mfma_f32_16x16x32_bf16(a1, b1, acc[1][1], 0, 0, 0);
    __syncthreads();
  }
#pragma unroll
  for (int fm = 0; fm < 2; fm++)
#pragma unroll
    for (int fn = 0; fn < 2; fn++) {
      int col = n0 + wc * 32 + fn * 16 + (lane & 15);
      float bcol = bias[col];
#pragma unroll
      for (int r = 0; r < 4; r++) {
        int rr = m0 + wr * 32 + fm * 16 + (lane >> 4) * 4 + r;
        C[(size_t)rr * FCN + col] = f2bf(acc[fm][fn][r] + bcol);
      }
    }
}

// ---------------- K10: column stats over [MQ,256] bf16 ----------------
__global__ __launch_bounds__(256) void k_stats256(const u16* __restrict__ X, float* __restrict__ cs,
                                                  float* __restrict__ cq) {
  int t = threadIdx.x; int r0 = blockIdx.x * 40;
  float s = 0, q = 0;
  for (int r = 0; r < 40; r++) {
    int rw = r0 + r; if (rw >= MQ) break;
    float v = bf2f(X[(size_t)rw * FCN + t]);
    s += v; q += v * v;
  }
  atomicAdd(&cs[t], s); atomicAdd(&cq[t], q);
}

// ---------------- K11: BN + ReLU over [MQ,256]; OUTF=0 -> bf16 y, OUTF=1 -> f32 y ----------------
template <int OUTF>
__global__ __launch_bounds__(256) void k_bn256(const u16* __restrict__ x, const float* __restrict__ cs,
                                               const float* __restrict__ cq, const float* __restrict__ g,
                                               const float* __restrict__ be, void* __restrict__ yv) {
  const float invn = 1.0f / (float)MQ;
  size_t total = (size_t)MQ * 128;  // pairs
  for (size_t i = (size_t)blockIdx.x * 256 + threadIdx.x; i < total; i += (size_t)gridDim.x * 256) {
    int c0 = ((int)(i & 127)) * 2;
    float m0 = cs[c0] * invn, m1 = cs[c0 + 1] * invn;
    float var0 = cq[c0] * invn - m0 * m0, var1 = cq[c0 + 1] * invn - m1 * m1;
    float sc0 = g[c0] * rsqrtf(var0 + EPS), sc1 = g[c0 + 1] * rsqrtf(var1 + EPS);
    float sh0 = be[c0] - m0 * sc0, sh1 = be[c0 + 1] - m1 * sc1;
    ushort2 u = *(const ushort2*)&x[i * 2];
    float y0 = fmaxf(bf2f(u.x) * sc0 + sh0, 0.0f), y1 = fmaxf(bf2f(u.y) * sc1 + sh1, 0.0f);
    if (OUTF) {
      float2 o; o.x = y0; o.y = y1;
      *(float2*)&((float*)yv)[i * 2] = o;
    } else {
      ushort2 o; o.x = f2bf(y0); o.y = f2bf(y1);
      *(ushort2*)&((u16*)yv)[i * 2] = o;
    }
  }
}

// ---------------- K12: fc4 + sigmoid (H3 f32 -> preds f32) ----------------
__global__ __launch_bounds__(256) void k_fc4(const float* __restrict__ H, const float* __restrict__ w4,
                                             const float* __restrict__ b4, float* __restrict__ preds) {
  int rowi = blockIdx.x * 4 + (threadIdx.x >> 6); int lane = threadIdx.x & 63;
  int c0 = lane * 4;
  float4 hv = *(const float4*)&H[(size_t)rowi * FCN + c0];
  float4 wv = *(const float4*)&w4[c0];
  float s = hv.x * wv.x + hv.y * wv.y + hv.z * wv.z + hv.w * wv.w;
  for (int o = 32; o >= 1; o >>= 1) s += __shfl_xor(s, o, 64);
  if (lane == 0) preds[rowi] = 1.0f / (1.0f + expf(-(s + b4[0])));
}

extern "C" void kernel_launch(void* const* d_in, const int* in_sizes, int n_in,
                              void* d_out, int out_size, void* d_ws, size_t ws_size,
                              hipStream_t stream) {
  const float* node_h = (const float*)d_in[0];
  const float* pg     = (const float*)d_in[1];
  const float* ne     = (const float*)d_in[2];
  // d_in[3] class_w unused by the reference
  const int* src = (const int*)d_in[4];
  const int* dst = (const int*)d_in[5];
  const int* ngr = (const int*)d_in[6];
  const float* w_init = (const float*)d_in[7];
  const float* b_init = (const float*)d_in[8];
  const float* g1  = (const float*)d_in[9];
  const float* be1 = (const float*)d_in[10];
  const float* g2  = (const float*)d_in[11];
  const float* be2 = (const float*)d_in[12];
  const float* w_fc  = (const float*)d_in[13];
  const float* b_fc  = (const float*)d_in[14];
  const float* w_fc2 = (const float*)d_in[15];
  const float* b_fc2 = (const float*)d_in[16];
  const float* w_fc3 = (const float*)d_in[17];
  const float* b_fc3 = (const float*)d_in[18];
  const float* w_fc4 = (const float*)d_in[19];
  const float* b_fc4 = (const float*)d_in[20];
  const float* gb  = (const float*)d_in[21];
  const float* bb  = (const float*)d_in[22];
  const float* gb2 = (const float*)d_in[23];
  const float* bb2 = (const float*)d_in[24];
  const float* gb3 = (const float*)d_in[25];
  const float* bb3 = (const float*)d_in[26];

  char* w = (char*)d_ws;
  u16* hA = (u16*)w;                                    // [N,512] bf16, 102.4 MB
  u16* hX = (u16*)(w + 102400000LL);                    // [N,512] bf16, 102.4 MB
  u16* Abuf = hX;                                       // [MQ,1536] bf16 31.5 MB (alias, hX dead)
  u16* X1 = (u16*)(w + 102400000LL + 33554432LL);
  u16* H1 = (u16*)(w + 102400000LL + 41943040LL);
  u16* X2 = (u16*)(w + 102400000LL + 50331648LL);
  u16* H2 = (u16*)(w + 102400000LL + 58720256LL);
  u16* X3 = (u16*)(w + 102400000LL + 67108864LL);
  size_t off = 204800000LL;
  int* deg = (int*)(w + off); off += 400128;
  float* st = (float*)(w + off); off += 16384;
  int* offs = (int*)(w + off); off += 400128;
  int* cursor = (int*)(w + off); off += 400128;
  int* nsrc = (int*)(w + off); off += 3200000;
  int* part = (int*)(w + off); off += 2048;
  u16* qemb = (u16*)(w + off); off += 1048576;
  // total ws use ~210.3 MB

  float *s_g1 = st,        *q_g1 = st + 512;
  float *s_g2 = st + 1024, *q_g2 = st + 1536;
  float *s_f1 = st + 2048, *q_f1 = st + 2304;
  float *s_f2 = st + 2560, *q_f2 = st + 2816;
  float *s_f3 = st + 3072, *q_f3 = st + 3328;

  float* preds = (float*)d_out;
  float* H3 = preds + MQ;  // f32 [MQ,256], part of d_out

  hipMemsetAsync(deg, 0, 400000, stream);
  hipMemsetAsync(st, 0, 14336, stream);

  k_init<<<6250, 256, 0, stream>>>(node_h, w_init, b_init, hA);
  k_deg<<<(NE + 255) / 256, 256, 0, stream>>>(dst, deg);
  k_scan_part<<<98, 256, 0, stream>>>(deg, part);
  k_scan_mid<<<1, 128, 0, stream>>>(part, 98, offs);
  k_scan_apply<<<98, 256, 0, stream>>>(deg, part, offs);
  k_copy<<<(NN + 255) / 256, 256, 0, stream>>>(offs, cursor);
  k_fill<<<(NE + 255) / 256, 256, 0, stream>>>(src, dst, cursor, nsrc);

  k_gin<<<(NN + 63) / 64, 256, 0, stream>>>(hA, offs, nsrc, hX, s_g1, q_g1);
  k_bn_hd<<<4096, 256, 0, stream>>>(hX, s_g1, q_g1, g1, be1, hA);
  k_gin<<<(NN + 63) / 64, 256, 0, stream>>>(hA, offs, nsrc, hX, s_g2, q_g2);
  k_bn_hd<<<4096, 256, 0, stream>>>(hX, s_g2, q_g2, g2, be2, hA);

  k_pool<<<NGRAPH, 256, 0, stream>>>(hA, ngr, qemb);
  k_buildA<<<(MQ * 384 + 255) / 256, 256, 0, stream>>>(qemb, pg, ne, Abuf);

  dim3 gg(160, 4);
  k_gemm<<<gg, 256, 0, stream>>>(Abuf, w_fc, b_fc, X1, 1536);
  k_stats256<<<256, 256, 0, stream>>>(X1, s_f1, q_f1);
  k_bn256<0><<<2048, 256, 0, stream>>>(X1, s_f1, q_f1, gb, bb, (void*)H1);

  k_gemm<<<gg, 256, 0, stream>>>(H1, w_fc2, b_fc2, X2, 256);
  k_stats256<<<256, 256, 0, stream>>>(X2, s_f2, q_f2);
  k_bn256<0><<<2048, 256, 0, stream>>>(X2, s_f2, q_f2, gb2, bb2, (void*)H2);

  k_gemm<<<gg, 256, 0, stream>>>(H2, w_fc3, b_fc3, X3, 256);
  k_stats256<<<256, 256, 0, stream>>>(X3, s_f3, q_f3);
  k_bn256<1><<<2048, 256, 0, stream>>>(X3, s_f3, q_f3, gb3, bb3, (void*)H3);

  k_fc4<<<2560, 256, 0, stream>>>(H3, w_fc4, b_fc4, preds);
}

// Round 3
// 768.846 us; speedup vs baseline: 1.3340x; 1.3340x over previous
//
#include <hip/hip_runtime.h>
#include <hip/hip_bf16.h>

typedef unsigned short u16;
typedef __bf16 bf16x8 __attribute__((ext_vector_type(8)));
typedef float f32x4 __attribute__((ext_vector_type(4)));

#define NN 100000
#define NE 800000
#define NGRAPH 1024
#define KREP 10
#define HD 512
#define MQ 10240
#define FCN 256
#define EPS 1e-5f

static __device__ __forceinline__ float bf2f(u16 u) {
  return __uint_as_float(((unsigned int)u) << 16);
}
static __device__ __forceinline__ u16 f2bf(float f) {
  __hip_bfloat16 h = __float2bfloat16(f);
  u16 u; __builtin_memcpy(&u, &h, 2); return u;
}
// accumulate 8 bf16 (packed in int4) into a[8]
static __device__ __forceinline__ void acc8(const int4& r, float a[8]) {
  const unsigned int* p = (const unsigned int*)&r;
#pragma unroll
  for (int k = 0; k < 4; k++) {
    unsigned int x = p[k];
    a[2 * k]     += __uint_as_float(x << 16);
    a[2 * k + 1] += __uint_as_float(x & 0xffff0000u);
  }
}

// ---------------- K1: h0 = node_h @ w_init + b_init  ([N,20]f32 x [20,512]f32 -> bf16) ----------------
__global__ __launch_bounds__(256) void k_init(const float* __restrict__ nh, const float* __restrict__ w,
                                              const float* __restrict__ bi, u16* __restrict__ h) {
  __shared__ float wls[20 * 512];
  __shared__ float als[16 * 20];
  int t = threadIdx.x;
  for (int i = t; i < 20 * 512; i += 256) wls[i] = w[i];
  int v0 = blockIdx.x * 16;
  for (int i = t; i < 16 * 20; i += 256) {
    int node = v0 + i / 20;
    als[i] = (node < NN) ? nh[node * 20 + i % 20] : 0.0f;
  }
  __syncthreads();
  int c0 = t * 2;
  float b0 = bi[c0], b1 = bi[c0 + 1];
  for (int ni = 0; ni < 16; ni++) {
    int v = v0 + ni; if (v >= NN) break;
    float s0 = b0, s1 = b1;
#pragma unroll
    for (int k = 0; k < 20; k++) {
      float a = als[ni * 20 + k];
      s0 += a * wls[k * 512 + c0];
      s1 += a * wls[k * 512 + c0 + 1];
    }
    ushort2 o; o.x = f2bf(s0); o.y = f2bf(s1);
    *(ushort2*)&h[(size_t)v * HD + c0] = o;
  }
}

// ---------------- CSR build ----------------
__global__ void k_deg(const int* __restrict__ dst, int* __restrict__ deg) {
  int i = blockIdx.x * 256 + threadIdx.x;
  if (i < NE) atomicAdd(&deg[dst[i]], 1);
}

__global__ __launch_bounds__(256) void k_scan_part(const int* __restrict__ deg, int* __restrict__ part) {
  __shared__ int ls[256];
  int t = threadIdx.x; int base = blockIdx.x * 1024;
  int s = 0;
  for (int i = t; i < 1024; i += 256) { int idx = base + i; if (idx < NN) s += deg[idx]; }
  ls[t] = s; __syncthreads();
  for (int o = 128; o > 0; o >>= 1) { if (t < o) ls[t] += ls[t + o]; __syncthreads(); }
  if (t == 0) part[blockIdx.x] = ls[0];
}

__global__ void k_scan_mid(int* part, int nb, int* offs) {
  __shared__ int ls[128];
  int t = threadIdx.x;
  if (t < nb) ls[t] = part[t];
  __syncthreads();
  if (t == 0) {
    int run = 0;
    for (int i = 0; i < nb; i++) { int v = ls[i]; ls[i] = run; run += v; }
  }
  __syncthreads();
  if (t < nb) part[t] = ls[t];
  if (t == 0) offs[NN] = NE;
}

__global__ __launch_bounds__(256) void k_scan_apply(const int* __restrict__ deg, const int* __restrict__ part,
                                                    int* __restrict__ offs, int* __restrict__ cursor) {
  __shared__ int ls[256];
  int t = threadIdx.x; int base = blockIdx.x * 1024 + t * 4;
  int v[4]; int s = 0;
#pragma unroll
  for (int j = 0; j < 4; j++) { int idx = base + j; v[j] = (idx < NN) ? deg[idx] : 0; s += v[j]; }
  ls[t] = s; __syncthreads();
  for (int o = 1; o < 256; o <<= 1) {
    int x = (t >= o) ? ls[t - o] : 0;
    __syncthreads();
    ls[t] += x;
    __syncthreads();
  }
  int excl = ls[t] - s + part[blockIdx.x];
#pragma unroll
  for (int j = 0; j < 4; j++) {
    int idx = base + j;
    if (idx < NN) { offs[idx] = excl; cursor[idx] = excl; }
    excl += v[j];
  }
}

__global__ void k_fill(const int* __restrict__ src, const int* __restrict__ dst,
                       int* __restrict__ cursor, int* __restrict__ nsrc) {
  int i = blockIdx.x * 256 + threadIdx.x;
  if (i < NE) { int p = atomicAdd(&cursor[dst[i]], 1); nsrc[p] = src[i]; }
}

// ---------------- K5: GIN mean gather + column stats — wave-per-node, 16B/lane, 4x unroll ----------------
__global__ __launch_bounds__(256) void k_gin(const u16* __restrict__ hin, const int* __restrict__ offs,
                                             const int* __restrict__ nsrc, u16* __restrict__ x,
                                             float* __restrict__ cs, float* __restrict__ cq) {
  __shared__ float redS[512];
  __shared__ float redQ[512];
  int t = threadIdx.x, wid = t >> 6, lane = t & 63;
  int c0 = lane * 8;
  for (int i = t; i < 512; i += 256) { redS[i] = 0.f; redQ[i] = 0.f; }
  __syncthreads();
  float s[8] = {0, 0, 0, 0, 0, 0, 0, 0}, q[8] = {0, 0, 0, 0, 0, 0, 0, 0};
  for (int v = blockIdx.x * 4 + wid; v < NN; v += gridDim.x * 4) {
    int e0 = offs[v], e1 = offs[v + 1];
    float a[8] = {0, 0, 0, 0, 0, 0, 0, 0};
    int e = e0;
    for (; e + 4 <= e1; e += 4) {
      int s0 = nsrc[e], s1 = nsrc[e + 1], s2 = nsrc[e + 2], s3 = nsrc[e + 3];
      int4 r0 = *(const int4*)&hin[(size_t)s0 * HD + c0];
      int4 r1 = *(const int4*)&hin[(size_t)s1 * HD + c0];
      int4 r2 = *(const int4*)&hin[(size_t)s2 * HD + c0];
      int4 r3 = *(const int4*)&hin[(size_t)s3 * HD + c0];
      acc8(r0, a); acc8(r1, a); acc8(r2, a); acc8(r3, a);
    }
    for (; e < e1; e++) {
      int sn = nsrc[e];
      int4 r = *(const int4*)&hin[(size_t)sn * HD + c0];
      acc8(r, a);
    }
    float inv = 1.0f / fmaxf((float)(e1 - e0), 1.0f);
    int4 hv = *(const int4*)&hin[(size_t)v * HD + c0];
    unsigned int ho[4];
#pragma unroll
    for (int k = 0; k < 4; k++) {
      unsigned int hw = ((unsigned int*)&hv)[k];
      float x0 = __uint_as_float(hw << 16) + a[2 * k] * inv;
      float x1 = __uint_as_float(hw & 0xffff0000u) + a[2 * k + 1] * inv;
      u16 b0 = f2bf(x0), b1 = f2bf(x1);
      ho[k] = ((unsigned int)b1 << 16) | (unsigned int)b0;
      float xr0 = bf2f(b0), xr1 = bf2f(b1);
      s[2 * k] += xr0; q[2 * k] += xr0 * xr0;
      s[2 * k + 1] += xr1; q[2 * k + 1] += xr1 * xr1;
    }
    *(int4*)&x[(size_t)v * HD + c0] = *(int4*)ho;
  }
#pragma unroll
  for (int j = 0; j < 8; j++) { atomicAdd(&redS[c0 + j], s[j]); atomicAdd(&redQ[c0 + j], q[j]); }
  __syncthreads();
  for (int i = t; i < 512; i += 256) { atomicAdd(&cs[i], redS[i]); atomicAdd(&cq[i], redQ[i]); }
}

// ---------------- K6: BN(train) + ReLU over [N,512] bf16 — 16B/lane ----------------
__global__ __launch_bounds__(256) void k_bn_hd(const u16* __restrict__ x, const float* __restrict__ cs,
                                               const float* __restrict__ cq, const float* __restrict__ g,
                                               const float* __restrict__ be, u16* __restrict__ y) {
  int lane = threadIdx.x & 63;
  int c0 = lane * 8;
  const float invn = 1.0f / (float)NN;
  float sc[8], sh[8];
#pragma unroll
  for (int j = 0; j < 8; j++) {
    float m = cs[c0 + j] * invn;
    float var = cq[c0 + j] * invn - m * m;
    sc[j] = g[c0 + j] * rsqrtf(var + EPS);
    sh[j] = be[c0 + j] - m * sc[j];
  }
  int wgid = (blockIdx.x * 256 + threadIdx.x) >> 6;
  int nw = (gridDim.x * 256) >> 6;
  for (int v = wgid; v < NN; v += nw) {
    int4 u = *(const int4*)&x[(size_t)v * HD + c0];
    unsigned int o[4];
#pragma unroll
    for (int k = 0; k < 4; k++) {
      unsigned int w = ((unsigned int*)&u)[k];
      float y0 = fmaxf(__uint_as_float(w << 16) * sc[2 * k] + sh[2 * k], 0.f);
      float y1 = fmaxf(__uint_as_float(w & 0xffff0000u) * sc[2 * k + 1] + sh[2 * k + 1], 0.f);
      o[k] = ((unsigned int)f2bf(y1) << 16) | (unsigned int)f2bf(y0);
    }
    *(int4*)&y[(size_t)v * HD + c0] = *(int4*)o;
  }
}

// ---------------- K7: per-graph mean pooling — wave-row-parallel ----------------
__global__ __launch_bounds__(256) void k_pool(const u16* __restrict__ h, const int* __restrict__ ngr,
                                              u16* __restrict__ qemb) {
  __shared__ float red[512];
  int g = blockIdx.x; int t = threadIdx.x, wid = t >> 6, lane = t & 63;
  int c0 = lane * 8;
  for (int i = t; i < 512; i += 256) red[i] = 0.f;
  int lo = 0, hi = NN;
  while (lo < hi) { int mid = (lo + hi) >> 1; if (ngr[mid] < g) lo = mid + 1; else hi = mid; }
  int s0_ = lo;
  hi = NN;
  while (lo < hi) { int mid = (lo + hi) >> 1; if (ngr[mid] < g + 1) lo = mid + 1; else hi = mid; }
  int e_ = lo;
  float a[8] = {0, 0, 0, 0, 0, 0, 0, 0};
  for (int v = s0_ + wid; v < e_; v += 4) {
    int4 r = *(const int4*)&h[(size_t)v * HD + c0];
    acc8(r, a);
  }
  __syncthreads();
#pragma unroll
  for (int j = 0; j < 8; j++) atomicAdd(&red[c0 + j], a[j]);
  __syncthreads();
  float inv = 1.0f / fmaxf((float)(e_ - s0_), 1.0f);
  int cc = t * 2;
  unsigned int o = ((unsigned int)f2bf(red[cc + 1] * inv) << 16) | (unsigned int)f2bf(red[cc] * inv);
  *(unsigned int*)&qemb[(size_t)g * HD + cc] = o;
}

// ---------------- K8: build A = [qemb | pg_emb | neigh_emb]  ([10240,1536] bf16) ----------------
__global__ void k_buildA(const u16* __restrict__ qemb, const float* __restrict__ pg,
                         const float* __restrict__ ne, u16* __restrict__ A) {
  int idx = blockIdx.x * 256 + threadIdx.x;  // chunks of 4 elems
  if (idx >= MQ * 384) return;
  int r = idx / 384; int cc = (idx % 384) * 4;
  int g = r / KREP;
  ushort4 o;
  if (cc < 512) {
    o = *(const ushort4*)&qemb[g * HD + cc];
  } else if (cc < 1024) {
    float4 v = *(const float4*)&pg[(size_t)g * HD + cc - 512];
    o.x = f2bf(v.x); o.y = f2bf(v.y); o.z = f2bf(v.z); o.w = f2bf(v.w);
  } else {
    float4 v = *(const float4*)&ne[(size_t)r * HD + cc - 1024];
    o.x = f2bf(v.x); o.y = f2bf(v.y); o.z = f2bf(v.z); o.w = f2bf(v.w);
  }
  *(ushort4*)&A[(size_t)idx * 4] = o;
}

// ---------------- K-cvt: weights f32 -> bf16 (w_fc, w_fc2, w_fc3 concatenated) ----------------
__global__ void k_cvtW(const float* __restrict__ w1, const float* __restrict__ w2,
                       const float* __restrict__ w3, u16* __restrict__ out) {
  int idx = (blockIdx.x * 256 + threadIdx.x) * 4;
  if (idx >= 524288) return;
  const float* src; int off;
  if (idx < 393216) { src = w1; off = idx; }
  else if (idx < 458752) { src = w2; off = idx - 393216; }
  else { src = w3; off = idx - 458752; }
  float4 v = *(const float4*)&src[off];
  ushort4 o; o.x = f2bf(v.x); o.y = f2bf(v.y); o.z = f2bf(v.z); o.w = f2bf(v.w);
  *(ushort4*)&out[idx] = o;
}

// ---------------- K9: GEMM C[M,256] = A[M,Kd](bf16) @ W[Kd,256](bf16) + bias, fused column stats ----------------
__global__ __launch_bounds__(256) void k_gemm(const u16* __restrict__ A, const u16* __restrict__ W,
                                              const float* __restrict__ bias, u16* __restrict__ C,
                                              float* __restrict__ cs, float* __restrict__ cq, int Kd) {
  __shared__ __align__(16) u16 Als[64][40];
  __shared__ __align__(16) u16 Bls[64][40];
  __shared__ float redS[64], redQ[64];
  int t = threadIdx.x; int wid = t >> 6; int lane = t & 63;
  int m0 = blockIdx.x * 64, n0 = blockIdx.y * 64;
  int wr = wid >> 1, wc = wid & 1;
  if (t < 64) { redS[t] = 0.f; redQ[t] = 0.f; }
  f32x4 zero = {0.0f, 0.0f, 0.0f, 0.0f};
  f32x4 acc[2][2];
#pragma unroll
  for (int i = 0; i < 2; i++)
#pragma unroll
    for (int j = 0; j < 2; j++) acc[i][j] = zero;
  int ar = t >> 2, akc = (t & 3) * 8;
  int bk = t >> 3, bnc = (t & 7) * 8;
  int row = lane & 15, kc = (lane >> 4) * 8;
  for (int k0 = 0; k0 < Kd; k0 += 32) {
    *(int4*)&Als[ar][akc] = *(const int4*)&A[(size_t)(m0 + ar) * Kd + k0 + akc];
    union { int4 v; u16 u[8]; } bv;
    bv.v = *(const int4*)&W[(size_t)(k0 + bk) * FCN + n0 + bnc];
#pragma unroll
    for (int j = 0; j < 8; j++) Bls[bnc + j][bk] = bv.u[j];
    __syncthreads();
    bf16x8 a0 = *(const bf16x8*)&Als[wr * 32 + row][kc];
    bf16x8 a1 = *(const bf16x8*)&Als[wr * 32 + 16 + row][kc];
    bf16x8 b0 = *(const bf16x8*)&Bls[wc * 32 + row][kc];
    bf16x8 b1 = *(const bf16x8*)&Bls[wc * 32 + 16 + row][kc];
    acc[0][0] = __builtin_amdgcn_mfma_f32_16x16x32_bf16(a0, b0, acc[0][0], 0, 0, 0);
    acc[0][1] = __builtin_amdgcn_mfma_f32_16x16x32_bf16(a0, b1, acc[0][1], 0, 0, 0);
    acc[1][0] = __builtin_amdgcn_mfma_f32_16x16x32_bf16(a1, b0, acc[1][0], 0, 0, 0);
    acc[1][1] = __builtin_amdgcn_mfma_f32_16x16x32_bf16(a1, b1, acc[1][1], 0, 0, 0);
    __syncthreads();
  }
#pragma unroll
  for (int fn = 0; fn < 2; fn++) {
    int cl = wc * 32 + fn * 16 + (lane & 15);
    int col = n0 + cl;
    float bcol = bias[col];
    float sS = 0.f, sQ = 0.f;
#pragma unroll
    for (int fm = 0; fm < 2; fm++) {
#pragma unroll
      for (int r = 0; r < 4; r++) {
        int rr = m0 + wr * 32 + fm * 16 + (lane >> 4) * 4 + r;
        u16 b = f2bf(acc[fm][fn][r] + bcol);
        C[(size_t)rr * FCN + col] = b;
        float xr = bf2f(b);
        sS += xr; sQ += xr * xr;
      }
    }
    atomicAdd(&redS[cl], sS);
    atomicAdd(&redQ[cl], sQ);
  }
  __syncthreads();
  if (t < 64) { atomicAdd(&cs[n0 + t], redS[t]); atomicAdd(&cq[n0 + t], redQ[t]); }
}

// ---------------- K11: BN + ReLU over [MQ,256] single-pass 8-wide; OUTF=1 -> f32 ----------------
template <int OUTF>
__global__ __launch_bounds__(256) void k_bn256(const u16* __restrict__ x, const float* __restrict__ cs,
                                               const float* __restrict__ cq, const float* __restrict__ g,
                                               const float* __restrict__ be, void* __restrict__ yv) {
  const float invn = 1.0f / (float)MQ;
  int tid = blockIdx.x * 256 + threadIdx.x;
  int r = tid >> 5; if (r >= MQ) return;
  int c0 = (tid & 31) * 8;
  float sc[8], sh[8];
#pragma unroll
  for (int j = 0; j < 8; j++) {
    float m = cs[c0 + j] * invn;
    float var = cq[c0 + j] * invn - m * m;
    sc[j] = g[c0 + j] * rsqrtf(var + EPS);
    sh[j] = be[c0 + j] - m * sc[j];
  }
  int4 u = *(const int4*)&x[(size_t)r * FCN + c0];
  float y[8];
#pragma unroll
  for (int k = 0; k < 4; k++) {
    unsigned int w = ((unsigned int*)&u)[k];
    y[2 * k]     = fmaxf(__uint_as_float(w << 16) * sc[2 * k] + sh[2 * k], 0.f);
    y[2 * k + 1] = fmaxf(__uint_as_float(w & 0xffff0000u) * sc[2 * k + 1] + sh[2 * k + 1], 0.f);
  }
  if (OUTF) {
    float* yp = (float*)yv;
    float4 o0 = {y[0], y[1], y[2], y[3]}, o1 = {y[4], y[5], y[6], y[7]};
    *(float4*)&yp[(size_t)r * FCN + c0] = o0;
    *(float4*)&yp[(size_t)r * FCN + c0 + 4] = o1;
  } else {
    unsigned int o[4];
#pragma unroll
    for (int k = 0; k < 4; k++)
      o[k] = ((unsigned int)f2bf(y[2 * k + 1]) << 16) | (unsigned int)f2bf(y[2 * k]);
    *(int4*)&((u16*)yv)[(size_t)r * FCN + c0] = *(int4*)o;
  }
}

// ---------------- K12: fc4 + sigmoid (H3 f32 -> preds f32) ----------------
__global__ __launch_bounds__(256) void k_fc4(const float* __restrict__ H, const float* __restrict__ w4,
                                             const float* __restrict__ b4, float* __restrict__ preds) {
  int rowi = blockIdx.x * 4 + (threadIdx.x >> 6); int lane = threadIdx.x & 63;
  int c0 = lane * 4;
  float4 hv = *(const float4*)&H[(size_t)rowi * FCN + c0];
  float4 wv = *(const float4*)&w4[c0];
  float s = hv.x * wv.x + hv.y * wv.y + hv.z * wv.z + hv.w * wv.w;
  for (int o = 32; o >= 1; o >>= 1) s += __shfl_xor(s, o, 64);
  if (lane == 0) preds[rowi] = 1.0f / (1.0f + expf(-(s + b4[0])));
}

extern "C" void kernel_launch(void* const* d_in, const int* in_sizes, int n_in,
                              void* d_out, int out_size, void* d_ws, size_t ws_size,
                              hipStream_t stream) {
  const float* node_h = (const float*)d_in[0];
  const float* pg     = (const float*)d_in[1];
  const float* ne     = (const float*)d_in[2];
  const int* src = (const int*)d_in[4];
  const int* dst = (const int*)d_in[5];
  const int* ngr = (const int*)d_in[6];
  const float* w_init = (const float*)d_in[7];
  const float* b_init = (const float*)d_in[8];
  const float* g1  = (const float*)d_in[9];
  const float* be1 = (const float*)d_in[10];
  const float* g2  = (const float*)d_in[11];
  const float* be2 = (const float*)d_in[12];
  const float* w_fc  = (const float*)d_in[13];
  const float* b_fc  = (const float*)d_in[14];
  const float* w_fc2 = (const float*)d_in[15];
  const float* b_fc2 = (const float*)d_in[16];
  const float* w_fc3 = (const float*)d_in[17];
  const float* b_fc3 = (const float*)d_in[18];
  const float* w_fc4 = (const float*)d_in[19];
  const float* b_fc4 = (const float*)d_in[20];
  const float* gb  = (const float*)d_in[21];
  const float* bb  = (const float*)d_in[22];
  const float* gb2 = (const float*)d_in[23];
  const float* bb2 = (const float*)d_in[24];
  const float* gb3 = (const float*)d_in[25];
  const float* bb3 = (const float*)d_in[26];

  char* w = (char*)d_ws;
  u16* hA = (u16*)w;                            // [N,512] bf16, 102.4 MB
  u16* hX = (u16*)(w + 102400000LL);            // [N,512] bf16, 102.4 MB (dead after bn_hd #2)
  u16* Abuf = hX;                               // [MQ,1536] bf16, 31.5 MB (alias into dead hX)
  u16* Wb = (u16*)(w + 150000000LL);            // 1.05 MB bf16 weights (alias into dead hX)
  u16* X1 = (u16*)(w + 102400000LL + 33554432LL);
  u16* H1 = (u16*)(w + 102400000LL + 41943040LL);
  u16* X2 = (u16*)(w + 102400000LL + 50331648LL);
  u16* H2 = (u16*)(w + 102400000LL + 58720256LL);
  u16* X3 = (u16*)(w + 102400000LL + 67108864LL);
  size_t off = 204800000LL;
  int* deg = (int*)(w + off); off += 400128;
  float* st = (float*)(w + off); off += 16384;
  int* offs = (int*)(w + off); off += 400128;
  int* cursor = (int*)(w + off); off += 400128;
  int* nsrc = (int*)(w + off); off += 3200000;
  int* part = (int*)(w + off); off += 2048;
  u16* qemb = (u16*)(w + off); off += 1048576;

  float *s_g1 = st,        *q_g1 = st + 512;
  float *s_g2 = st + 1024, *q_g2 = st + 1536;
  float *s_f1 = st + 2048, *q_f1 = st + 2304;
  float *s_f2 = st + 2560, *q_f2 = st + 2816;
  float *s_f3 = st + 3072, *q_f3 = st + 3328;

  u16* Wb1 = Wb;
  u16* Wb2 = Wb + 393216;
  u16* Wb3 = Wb + 458752;

  float* preds = (float*)d_out;
  float* H3 = preds + MQ;  // f32 [MQ,256], part of d_out

  hipMemsetAsync(deg, 0, 400128, stream);
  hipMemsetAsync(st, 0, 16384, stream);

  k_init<<<6250, 256, 0, stream>>>(node_h, w_init, b_init, hA);
  k_deg<<<(NE + 255) / 256, 256, 0, stream>>>(dst, deg);
  k_scan_part<<<98, 256, 0, stream>>>(deg, part);
  k_scan_mid<<<1, 128, 0, stream>>>(part, 98, offs);
  k_scan_apply<<<98, 256, 0, stream>>>(deg, part, offs, cursor);
  k_fill<<<(NE + 255) / 256, 256, 0, stream>>>(src, dst, cursor, nsrc);

  k_gin<<<2048, 256, 0, stream>>>(hA, offs, nsrc, hX, s_g1, q_g1);
  k_bn_hd<<<2048, 256, 0, stream>>>(hX, s_g1, q_g1, g1, be1, hA);
  k_gin<<<2048, 256, 0, stream>>>(hA, offs, nsrc, hX, s_g2, q_g2);
  k_bn_hd<<<2048, 256, 0, stream>>>(hX, s_g2, q_g2, g2, be2, hA);

  k_cvtW<<<512, 256, 0, stream>>>(w_fc, w_fc2, w_fc3, Wb);
  k_pool<<<NGRAPH, 256, 0, stream>>>(hA, ngr, qemb);
  k_buildA<<<(MQ * 384 + 255) / 256, 256, 0, stream>>>(qemb, pg, ne, Abuf);

  dim3 gg(160, 4);
  k_gemm<<<gg, 256, 0, stream>>>(Abuf, Wb1, b_fc, X1, s_f1, q_f1, 1536);
  k_bn256<0><<<1280, 256, 0, stream>>>(X1, s_f1, q_f1, gb, bb, (void*)H1);

  k_gemm<<<gg, 256, 0, stream>>>(H1, Wb2, b_fc2, X2, s_f2, q_f2, 256);
  k_bn256<0><<<1280, 256, 0, stream>>>(X2, s_f2, q_f2, gb2, bb2, (void*)H2);

  k_gemm<<<gg, 256, 0, stream>>>(H2, Wb3, b_fc3, X3, s_f3, q_f3, 256);
  k_bn256<1><<<1280, 256, 0, stream>>>(X3, s_f3, q_f3, gb3, bb3, (void*)H3);

  k_fc4<<<2560, 256, 0, stream>>>(H3, w_fc4, b_fc4, preds);
}